// Round 1
// baseline (10374.475 us; speedup 1.0000x reference)
//
#include <hip/hip_runtime.h>
#include <hip/hip_bf16.h>
#include <math.h>

// Problem constants (from reference):
#define NHEADS 16
#define HD     128
#define CEMB   2048
#define BATCH  4
#define TSEQ   2048

// ---------------- Flash attention with exact-floor scores ----------------
// grid (T/TQ, B*H), block 256 (4 waves).
// Thread t: row r = t>>3 (0..31), group g = t&7.
//   - computes score cols c = g + 8*cc (cc 0..3) for row r
//   - accumulates O cols 4*g + 32*cv + e (cv 0..3, e 0..3) for row r
#define TQ 32
#define TK 32
#define LK 132            // LDS row stride (floats): 128 + 4 -> 16B aligned, conflict-free patterns
#define NEGF (-1.0e30f)
#define FLOOR_WIN 2e-3f   // fp32 worst-case dot error is ~2.4e-4 in score units; 2e-3 is safe

__global__ __launch_bounds__(256)
void attn_kernel(const float* __restrict__ Q, const float* __restrict__ K,
                 const float* __restrict__ V, float* __restrict__ O)
{
    __shared__ float Qs[TQ][LK];
    __shared__ float Ks[TK][LK];
    __shared__ float Vs[TK][LK];
    __shared__ float Ps[TQ][TK + 4];

    const int tid = threadIdx.x;
    const int bh  = blockIdx.y;
    const int b   = bh >> 4;
    const int h   = bh & 15;
    const int q0  = blockIdx.x * TQ;

    const float  scale  = sqrtf(128.0f);      // fp32 scalar, matches np.sqrt(hd).astype(float32)
    const double dscale = (double)scale;

    const int r = tid >> 3;   // row within Q tile
    const int g = tid & 7;

    // ---- load Q tile (32 rows x 128) coalesced float4 ----
    {
        const size_t base = ((size_t)b * TSEQ) * CEMB + (size_t)h * HD;
        #pragma unroll
        for (int i = 0; i < 4; ++i) {
            int idx = tid + 256 * i;          // 0..1023
            int row = idx >> 5;               // 0..31
            int kv  = idx & 31;               // 0..31 float4s per row
            float4 val = *(const float4*)(Q + base + (size_t)(q0 + row) * CEMB + 4 * kv);
            *(float4*)&Qs[row][4 * kv] = val;
        }
    }

    float m_r = NEGF;
    float l_r = 0.0f;
    float4 oa[4];
    #pragma unroll
    for (int cv = 0; cv < 4; ++cv) oa[cv] = make_float4(0.f, 0.f, 0.f, 0.f);

    const int qrow = q0 + r;
    const int nkt  = blockIdx.x + 1;   // causal: K tiles 0..blockIdx.x

    for (int kt = 0; kt < nkt; ++kt) {
        const int k0 = kt * TK;
        __syncthreads();   // previous iteration's Vs/Ps reads complete
        {
            const size_t base = ((size_t)b * TSEQ) * CEMB + (size_t)h * HD;
            #pragma unroll
            for (int i = 0; i < 4; ++i) {
                int idx = tid + 256 * i;
                int row = idx >> 5;
                int kv  = idx & 31;
                size_t off = base + (size_t)(k0 + row) * CEMB + 4 * kv;
                *(float4*)&Ks[row][4 * kv] = *(const float4*)(K + off);
                *(float4*)&Vs[row][4 * kv] = *(const float4*)(V + off);
            }
        }
        __syncthreads();

        // ---- scores: 4 dots per thread, fp32 with fp64 boundary fixup ----
        float sc[4];
        float dot[4] = {0.f, 0.f, 0.f, 0.f};
        #pragma unroll
        for (int kv = 0; kv < 32; ++kv) {
            float4 qa = *(const float4*)&Qs[r][4 * kv];
            #pragma unroll
            for (int cc = 0; cc < 4; ++cc) {
                const float4 kb = *(const float4*)&Ks[g + 8 * cc][4 * kv];
                dot[cc] += qa.x * kb.x + qa.y * kb.y + qa.z * kb.z + qa.w * kb.w;
            }
        }
        float tmax = NEGF;
        #pragma unroll
        for (int cc = 0; cc < 4; ++cc) {
            int c = g + 8 * cc;
            if (k0 + c > qrow) { sc[cc] = NEGF; continue; }
            float s = dot[cc] / scale;
            float f = floorf(s);
            float frac = s - f;
            if (frac < FLOOR_WIN || frac > 1.0f - FLOOR_WIN) {
                // rare (~0.4%): recompute dot in fp64 -> floor exact vs fp64 reference
                double dd = 0.0;
                for (int kk = 0; kk < HD; ++kk)
                    dd += (double)Qs[r][kk] * (double)Ks[c][kk];
                f = (float)floor(dd / dscale);
            }
            sc[cc] = f;
            tmax = fmaxf(tmax, f);
        }
        // row max across the 8-lane group
        #pragma unroll
        for (int off = 1; off < 8; off <<= 1)
            tmax = fmaxf(tmax, __shfl_xor(tmax, off, 8));

        float m_new = fmaxf(m_r, tmax);                 // always finite (>=1 valid col per row)
        float alpha = (m_r <= NEGF * 0.5f) ? 0.0f : expf(m_r - m_new);
        float p[4];
        float psum = 0.f;
        #pragma unroll
        for (int cc = 0; cc < 4; ++cc) {
            p[cc] = (sc[cc] <= NEGF * 0.5f) ? 0.0f : expf(sc[cc] - m_new);
            psum += p[cc];
        }
        #pragma unroll
        for (int off = 1; off < 8; off <<= 1)
            psum += __shfl_xor(psum, off, 8);
        l_r = l_r * alpha + psum;
        m_r = m_new;
        #pragma unroll
        for (int cc = 0; cc < 4; ++cc) Ps[r][g + 8 * cc] = p[cc];
        __syncthreads();

        // ---- O = O*alpha + P · V ----
        #pragma unroll
        for (int cv = 0; cv < 4; ++cv) {
            oa[cv].x *= alpha; oa[cv].y *= alpha; oa[cv].z *= alpha; oa[cv].w *= alpha;
        }
        for (int j = 0; j < TK; ++j) {
            float pj = Ps[r][j];
            #pragma unroll
            for (int cv = 0; cv < 4; ++cv) {
                const float4 vv = *(const float4*)&Vs[j][4 * g + 32 * cv];
                oa[cv].x += pj * vv.x; oa[cv].y += pj * vv.y;
                oa[cv].z += pj * vv.z; oa[cv].w += pj * vv.w;
            }
        }
    }

    // ---- normalize + write merged-head layout [b, t, h*128 + c] ----
    const float inv_l = 1.0f / l_r;
    const size_t obase = ((size_t)b * TSEQ + qrow) * CEMB + (size_t)h * HD;
    #pragma unroll
    for (int cv = 0; cv < 4; ++cv) {
        float4 o = oa[cv];
        o.x *= inv_l; o.y *= inv_l; o.z *= inv_l; o.w *= inv_l;
        *(float4*)(O + obase + 4 * g + 32 * cv) = o;
    }
}

// ---------------- projection: out = X @ W^T + bias ----------------
// X: (8192, 2048) fp32 (attn output in ws), W: (2048, 2048) row-major, out: (8192, 2048)
// Tile 64x64x32, block 256 (16x16 threads), 4x4 micro-tile.
#define PBK 32
#define PLK 68   // LDS stride for transposed tiles: 64 + 4, 16B aligned

__global__ __launch_bounds__(256)
void proj_kernel(const float* __restrict__ X, const float* __restrict__ W,
                 const float* __restrict__ bias, float* __restrict__ out)
{
    __shared__ float As[PBK][PLK];   // As[kk][row]
    __shared__ float Bs[PBK][PLK];   // Bs[kk][col]

    const int tid = threadIdx.x;
    const int tx = tid & 15;
    const int ty = tid >> 4;
    const int m0 = blockIdx.y * 64;
    const int n0 = blockIdx.x * 64;

    float acc[4][4];
    #pragma unroll
    for (int i = 0; i < 4; ++i)
        #pragma unroll
        for (int j = 0; j < 4; ++j) acc[i][j] = 0.f;

    for (int k0 = 0; k0 < CEMB; k0 += PBK) {
        __syncthreads();
        #pragma unroll
        for (int i = 0; i < 2; ++i) {
            int idx = tid + 256 * i;    // 0..511
            int row = idx >> 3;         // 0..63
            int kv  = idx & 7;          // 0..7 float4s of the 32-wide K slab
            float4 xa = *(const float4*)(X + (size_t)(m0 + row) * CEMB + k0 + 4 * kv);
            float4 wa = *(const float4*)(W + (size_t)(n0 + row) * CEMB + k0 + 4 * kv);
            As[4 * kv + 0][row] = xa.x; As[4 * kv + 1][row] = xa.y;
            As[4 * kv + 2][row] = xa.z; As[4 * kv + 3][row] = xa.w;
            Bs[4 * kv + 0][row] = wa.x; Bs[4 * kv + 1][row] = wa.y;
            Bs[4 * kv + 2][row] = wa.z; Bs[4 * kv + 3][row] = wa.w;
        }
        __syncthreads();
        #pragma unroll
        for (int kk = 0; kk < PBK; ++kk) {
            float4 a = *(const float4*)&As[kk][4 * ty];
            float4 bb = *(const float4*)&Bs[kk][4 * tx];
            acc[0][0] += a.x * bb.x; acc[0][1] += a.x * bb.y; acc[0][2] += a.x * bb.z; acc[0][3] += a.x * bb.w;
            acc[1][0] += a.y * bb.x; acc[1][1] += a.y * bb.y; acc[1][2] += a.y * bb.z; acc[1][3] += a.y * bb.w;
            acc[2][0] += a.z * bb.x; acc[2][1] += a.z * bb.y; acc[2][2] += a.z * bb.z; acc[2][3] += a.z * bb.w;
            acc[3][0] += a.w * bb.x; acc[3][1] += a.w * bb.y; acc[3][2] += a.w * bb.z; acc[3][3] += a.w * bb.w;
        }
    }

    const float4 bb = *(const float4*)(bias + n0 + 4 * tx);
    #pragma unroll
    for (int e = 0; e < 4; ++e) {
        float4 o;
        o.x = acc[e][0] + bb.x; o.y = acc[e][1] + bb.y;
        o.z = acc[e][2] + bb.z; o.w = acc[e][3] + bb.w;
        *(float4*)(out + (size_t)(m0 + 4 * ty + e) * CEMB + n0 + 4 * tx) = o;
    }
}

extern "C" void kernel_launch(void* const* d_in, const int* in_sizes, int n_in,
                              void* d_out, int out_size, void* d_ws, size_t ws_size,
                              hipStream_t stream)
{
    // setup_inputs order: v, k, q, W_out, b_out
    const float* v    = (const float*)d_in[0];
    const float* k    = (const float*)d_in[1];
    const float* q    = (const float*)d_in[2];
    const float* W    = (const float*)d_in[3];
    const float* bias = (const float*)d_in[4];

    float* attn = (float*)d_ws;        // B*T*C fp32 = 64 MiB scratch
    float* out  = (float*)d_out;

    dim3 agrid(TSEQ / TQ, BATCH * NHEADS);   // (64, 64)
    attn_kernel<<<agrid, 256, 0, stream>>>(q, k, v, attn);

    dim3 pgrid(CEMB / 64, (BATCH * TSEQ) / 64);  // (32, 128)
    proj_kernel<<<pgrid, 256, 0, stream>>>(attn, W, bias, out);
}

// Round 2
// 2255.775 us; speedup vs baseline: 4.5991x; 4.5991x over previous
//
#include <hip/hip_runtime.h>
#include <hip/hip_bf16.h>
#include <math.h>

#define NHEADS 16
#define HD     128
#define CEMB   2048
#define BATCH  4
#define TSEQ   2048

typedef __attribute__((ext_vector_type(8))) short bf16x8;
typedef __attribute__((ext_vector_type(4))) float f32x4;

#define NEGF (-1.0e30f)
#define WIN  2.5e-4f     // fp64 fixup window in score units; 3-term bf16-split err ~2e-5 typ

__device__ inline short f2bf(float x) {
    __hip_bfloat16 h = __float2bfloat16(x);
    return *reinterpret_cast<short*>(&h);
}
__device__ inline float bf2f(short s) {
    __hip_bfloat16 h = *reinterpret_cast<__hip_bfloat16*>(&s);
    return __bfloat162float(h);
}
__device__ inline void split2(float x, short& hi, short& lo) {
    __hip_bfloat16 h = __float2bfloat16(x);
    float hf = __bfloat162float(h);
    __hip_bfloat16 l = __float2bfloat16(x - hf);
    hi = *reinterpret_cast<short*>(&h);
    lo = *reinterpret_cast<short*>(&l);
}

// ---------------- MFMA flash attention with exact-floor scores ----------------
// Block = 256 threads = 4 waves. Wave w owns 32 q-rows (two 16-row MFMA sub-tiles).
// Block covers 128 q-rows. K-tiles of 32 cols, staged hi/lo bf16 in LDS.
// Layouts (verified per guide §3): A-frag A[m=lane&15][k=quad*8+j];
// B-frag B[k=quad*8+j][n=lane&15]; C/D row=quad*4+reg, col=lane&15.
__global__ __launch_bounds__(256, 2)
void attn_mfma(const float* __restrict__ Q, const float* __restrict__ K,
               const float* __restrict__ V, float* __restrict__ O)
{
    // LDS strides: Khi/Klo 136 bf16 (272B, 16B-aligned rows, 2-way max on frag reads)
    // Vs 132 bf16 (b16 gather reads: 2-way max), Ps 40 bf16 (80B rows, 16B-aligned)
    __shared__ __align__(16) short Khi[32][136];
    __shared__ __align__(16) short Klo[32][136];
    __shared__ __align__(16) short Vs[32][132];
    __shared__ __align__(16) short Ps[4][32][40];

    const int tid  = threadIdx.x;
    const int wave = tid >> 6;
    const int lane = tid & 63;
    const int quad = lane >> 4;
    const int n    = lane & 15;

    const int bh = blockIdx.y;
    const int b  = bh >> 4;
    const int h  = bh & 15;
    // reverse q-block order so the heaviest (most K-tiles) blocks launch first
    const int qblk = (int)gridDim.x - 1 - (int)blockIdx.x;
    const int q0b  = qblk * 128;
    const int q0w  = q0b + wave * 32;

    const size_t inbase = ((size_t)b * TSEQ) * CEMB + (size_t)h * HD;

    const float  scale     = sqrtf(128.0f);
    const double dscale    = (double)scale;
    const float  inv_scale = 1.0f / scale;

    // ---- Q fragments (resident): hi/lo bf16 split, per sub-tile s and k-step ks ----
    bf16x8 qhi[2][4], qlo[2][4];
    #pragma unroll
    for (int s = 0; s < 2; ++s) {
        #pragma unroll
        for (int ks = 0; ks < 4; ++ks) {
            const float* qp = Q + inbase + (size_t)(q0w + 16 * s + n) * CEMB + 32 * ks + 8 * quad;
            float4 f0 = *(const float4*)qp;
            float4 f1 = *(const float4*)(qp + 4);
            float fv[8] = {f0.x, f0.y, f0.z, f0.w, f1.x, f1.y, f1.z, f1.w};
            bf16x8 h8, l8;
            #pragma unroll
            for (int j = 0; j < 8; ++j) {
                short hj, lj;
                split2(fv[j], hj, lj);
                h8[j] = hj; l8[j] = lj;
            }
            qhi[s][ks] = h8;
            qlo[s][ks] = l8;
        }
    }

    f32x4 oacc[2][8];
    #pragma unroll
    for (int s = 0; s < 2; ++s)
        #pragma unroll
        for (int nt = 0; nt < 8; ++nt)
            oacc[s][nt] = (f32x4){0.f, 0.f, 0.f, 0.f};

    float m_r[2][4], l_r[2][4];
    #pragma unroll
    for (int s = 0; s < 2; ++s)
        #pragma unroll
        for (int reg = 0; reg < 4; ++reg) { m_r[s][reg] = NEGF; l_r[s][reg] = 0.f; }

    const int nkt = 4 * (qblk + 1);   // K-tiles covering the block's 128 rows

    for (int kt = 0; kt < nkt; ++kt) {
        const int k0 = kt * 32;
        __syncthreads();   // previous iteration's LDS reads complete
        // ---- stage K (hi/lo split) and V (bf16) ----
        #pragma unroll
        for (int i = 0; i < 4; ++i) {
            int idx = tid + 256 * i;       // 0..1023
            int r   = idx >> 5;            // 0..31
            int c4  = idx & 31;            // float4 within row
            size_t off = inbase + (size_t)(k0 + r) * CEMB + 4 * c4;
            float4 kv = *(const float4*)(K + off);
            float4 vv = *(const float4*)(V + off);
            short4 khi4, klo4, v4;
            split2(kv.x, khi4.x, klo4.x); split2(kv.y, khi4.y, klo4.y);
            split2(kv.z, khi4.z, klo4.z); split2(kv.w, khi4.w, klo4.w);
            v4.x = f2bf(vv.x); v4.y = f2bf(vv.y); v4.z = f2bf(vv.z); v4.w = f2bf(vv.w);
            *(short4*)&Khi[r][4 * c4] = khi4;
            *(short4*)&Klo[r][4 * c4] = klo4;
            *(short4*)&Vs[r][4 * c4]  = v4;
        }
        __syncthreads();

        if (k0 <= q0w + 31) {   // causal: this wave has live rows in this K-tile
            // ---- S = Q·K^T via 3-term bf16-split MFMA ----
            f32x4 sacc[2][2];
            #pragma unroll
            for (int s = 0; s < 2; ++s)
                #pragma unroll
                for (int nt = 0; nt < 2; ++nt)
                    sacc[s][nt] = (f32x4){0.f, 0.f, 0.f, 0.f};

            #pragma unroll
            for (int ks = 0; ks < 4; ++ks) {
                #pragma unroll
                for (int nt = 0; nt < 2; ++nt) {
                    bf16x8 khf = *(const bf16x8*)&Khi[16 * nt + n][32 * ks + 8 * quad];
                    bf16x8 klf = *(const bf16x8*)&Klo[16 * nt + n][32 * ks + 8 * quad];
                    #pragma unroll
                    for (int s = 0; s < 2; ++s) {
                        sacc[s][nt] = __builtin_amdgcn_mfma_f32_16x16x32_bf16(qhi[s][ks], khf, sacc[s][nt], 0, 0, 0);
                        sacc[s][nt] = __builtin_amdgcn_mfma_f32_16x16x32_bf16(qhi[s][ks], klf, sacc[s][nt], 0, 0, 0);
                        sacc[s][nt] = __builtin_amdgcn_mfma_f32_16x16x32_bf16(qlo[s][ks], khf, sacc[s][nt], 0, 0, 0);
                    }
                }
            }

            // ---- floor + fp64 boundary fixup + online softmax, write P ----
            #pragma unroll
            for (int s = 0; s < 2; ++s) {
                float sc[2][4];
                #pragma unroll
                for (int nt = 0; nt < 2; ++nt) {
                    #pragma unroll
                    for (int reg = 0; reg < 4; ++reg) {
                        int qrow = q0w + 16 * s + 4 * quad + reg;
                        int kcol = k0 + 16 * nt + n;
                        if (kcol > qrow) { sc[nt][reg] = NEGF; continue; }
                        float sv = sacc[s][nt][reg] * inv_scale;
                        float f  = floorf(sv);
                        float fr = sv - f;
                        if (fr < WIN || fr > 1.0f - WIN) {
                            // rare: exact fp64 dot from original fp32 globals
                            const float* qp = Q + inbase + (size_t)qrow * CEMB;
                            const float* kp = K + inbase + (size_t)kcol * CEMB;
                            double dd = 0.0;
                            for (int kk = 0; kk < HD; kk += 4)
                                dd += (double)qp[kk] * kp[kk] + (double)qp[kk + 1] * kp[kk + 1]
                                    + (double)qp[kk + 2] * kp[kk + 2] + (double)qp[kk + 3] * kp[kk + 3];
                            f = (float)floor(dd / dscale);
                        }
                        sc[nt][reg] = f;
                    }
                }
                float alphaL[4];
                #pragma unroll
                for (int reg = 0; reg < 4; ++reg) {
                    float tm = fmaxf(sc[0][reg], sc[1][reg]);
                    tm = fmaxf(tm, __shfl_xor(tm, 1));
                    tm = fmaxf(tm, __shfl_xor(tm, 2));
                    tm = fmaxf(tm, __shfl_xor(tm, 4));
                    tm = fmaxf(tm, __shfl_xor(tm, 8));
                    float mo = m_r[s][reg];
                    float mn = fmaxf(mo, tm);
                    float al = (mo < -1e29f) ? 0.0f : expf(mo - mn);
                    float p0 = (sc[0][reg] < -1e29f) ? 0.0f : expf(sc[0][reg] - mn);
                    float p1 = (sc[1][reg] < -1e29f) ? 0.0f : expf(sc[1][reg] - mn);
                    float ps = p0 + p1;
                    ps += __shfl_xor(ps, 1);
                    ps += __shfl_xor(ps, 2);
                    ps += __shfl_xor(ps, 4);
                    ps += __shfl_xor(ps, 8);
                    l_r[s][reg] = l_r[s][reg] * al + ps;
                    m_r[s][reg] = mn;
                    alphaL[reg] = al;
                    Ps[wave][16 * s + 4 * quad + reg][n]      = f2bf(p0);
                    Ps[wave][16 * s + 4 * quad + reg][16 + n] = f2bf(p1);
                }
                #pragma unroll
                for (int ntv = 0; ntv < 8; ++ntv) {
                    #pragma unroll
                    for (int reg = 0; reg < 4; ++reg)
                        oacc[s][ntv][reg] *= alphaL[reg];
                }
            }

            // ---- O += P·V (P round-trips LDS C-layout -> A-layout, wave-private) ----
            bf16x8 pfa[2];
            pfa[0] = *(const bf16x8*)&Ps[wave][n][8 * quad];
            pfa[1] = *(const bf16x8*)&Ps[wave][16 + n][8 * quad];
            #pragma unroll
            for (int ntv = 0; ntv < 8; ++ntv) {
                bf16x8 vf;
                #pragma unroll
                for (int j = 0; j < 8; ++j)
                    vf[j] = Vs[8 * quad + j][16 * ntv + n];   // B[k=krow][n=hd] gather, 2-way banks
                oacc[0][ntv] = __builtin_amdgcn_mfma_f32_16x16x32_bf16(pfa[0], vf, oacc[0][ntv], 0, 0, 0);
                oacc[1][ntv] = __builtin_amdgcn_mfma_f32_16x16x32_bf16(pfa[1], vf, oacc[1][ntv], 0, 0, 0);
            }
        }
    }

    // ---- normalize + write merged-head layout [b, t, h*128 + c] ----
    #pragma unroll
    for (int s = 0; s < 2; ++s) {
        #pragma unroll
        for (int reg = 0; reg < 4; ++reg) {
            float inv = 1.0f / l_r[s][reg];
            int qrow = q0w + 16 * s + 4 * quad + reg;
            float* op = O + ((size_t)b * TSEQ + qrow) * CEMB + (size_t)h * HD;
            #pragma unroll
            for (int ntv = 0; ntv < 8; ++ntv)
                op[16 * ntv + n] = oacc[s][ntv][reg] * inv;
        }
    }
}

// ---------------- projection: out = X @ W^T + bias (unchanged scalar fp32) ----------------
#define PBK 32
#define PLK 68

__global__ __launch_bounds__(256)
void proj_kernel(const float* __restrict__ X, const float* __restrict__ W,
                 const float* __restrict__ bias, float* __restrict__ out)
{
    __shared__ float As[PBK][PLK];
    __shared__ float Bs[PBK][PLK];

    const int tid = threadIdx.x;
    const int tx = tid & 15;
    const int ty = tid >> 4;
    const int m0 = blockIdx.y * 64;
    const int n0 = blockIdx.x * 64;

    float acc[4][4];
    #pragma unroll
    for (int i = 0; i < 4; ++i)
        #pragma unroll
        for (int j = 0; j < 4; ++j) acc[i][j] = 0.f;

    for (int k0 = 0; k0 < CEMB; k0 += PBK) {
        __syncthreads();
        #pragma unroll
        for (int i = 0; i < 2; ++i) {
            int idx = tid + 256 * i;
            int row = idx >> 3;
            int kv  = idx & 7;
            float4 xa = *(const float4*)(X + (size_t)(m0 + row) * CEMB + k0 + 4 * kv);
            float4 wa = *(const float4*)(W + (size_t)(n0 + row) * CEMB + k0 + 4 * kv);
            As[4 * kv + 0][row] = xa.x; As[4 * kv + 1][row] = xa.y;
            As[4 * kv + 2][row] = xa.z; As[4 * kv + 3][row] = xa.w;
            Bs[4 * kv + 0][row] = wa.x; Bs[4 * kv + 1][row] = wa.y;
            Bs[4 * kv + 2][row] = wa.z; Bs[4 * kv + 3][row] = wa.w;
        }
        __syncthreads();
        #pragma unroll
        for (int kk = 0; kk < PBK; ++kk) {
            float4 a  = *(const float4*)&As[kk][4 * ty];
            float4 bb = *(const float4*)&Bs[kk][4 * tx];
            acc[0][0] += a.x * bb.x; acc[0][1] += a.x * bb.y; acc[0][2] += a.x * bb.z; acc[0][3] += a.x * bb.w;
            acc[1][0] += a.y * bb.x; acc[1][1] += a.y * bb.y; acc[1][2] += a.y * bb.z; acc[1][3] += a.y * bb.w;
            acc[2][0] += a.z * bb.x; acc[2][1] += a.z * bb.y; acc[2][2] += a.z * bb.z; acc[2][3] += a.z * bb.w;
            acc[3][0] += a.w * bb.x; acc[3][1] += a.w * bb.y; acc[3][2] += a.w * bb.z; acc[3][3] += a.w * bb.w;
        }
    }

    const float4 bb = *(const float4*)(bias + n0 + 4 * tx);
    #pragma unroll
    for (int e = 0; e < 4; ++e) {
        float4 o;
        o.x = acc[e][0] + bb.x; o.y = acc[e][1] + bb.y;
        o.z = acc[e][2] + bb.z; o.w = acc[e][3] + bb.w;
        *(float4*)(out + (size_t)(m0 + 4 * ty + e) * CEMB + n0 + 4 * tx) = o;
    }
}

extern "C" void kernel_launch(void* const* d_in, const int* in_sizes, int n_in,
                              void* d_out, int out_size, void* d_ws, size_t ws_size,
                              hipStream_t stream)
{
    // setup_inputs order: v, k, q, W_out, b_out
    const float* v    = (const float*)d_in[0];
    const float* k    = (const float*)d_in[1];
    const float* q    = (const float*)d_in[2];
    const float* W    = (const float*)d_in[3];
    const float* bias = (const float*)d_in[4];

    float* attn = (float*)d_ws;   // B*T*C fp32 = 64 MiB scratch
    float* out  = (float*)d_out;

    dim3 agrid(TSEQ / 128, BATCH * NHEADS);   // (16, 64)
    attn_mfma<<<agrid, 256, 0, stream>>>(q, k, v, attn);

    dim3 pgrid(CEMB / 64, (BATCH * TSEQ) / 64);  // (32, 128)
    proj_kernel<<<pgrid, 256, 0, stream>>>(attn, W, bias, out);
}

// Round 3
// 1935.094 us; speedup vs baseline: 5.3612x; 1.1657x over previous
//
#include <hip/hip_runtime.h>
#include <hip/hip_bf16.h>
#include <math.h>

#define NHEADS 16
#define HD     128
#define CEMB   2048
#define BATCH  4
#define TSEQ   2048

typedef __attribute__((ext_vector_type(8))) short bf16x8;
typedef __attribute__((ext_vector_type(4))) float f32x4;

#define NEGF (-1.0e30f)
#define WIN  2.5e-4f     // fp64 fixup window in score units; 3-term bf16-split err ~2e-5 typ

__device__ inline short f2bf(float x) {
    __hip_bfloat16 h = __float2bfloat16(x);
    return *reinterpret_cast<short*>(&h);
}
__device__ inline void split2(float x, short& hi, short& lo) {
    __hip_bfloat16 h = __float2bfloat16(x);
    float hf = __bfloat162float(h);
    __hip_bfloat16 l = __float2bfloat16(x - hf);
    hi = *reinterpret_cast<short*>(&h);
    lo = *reinterpret_cast<short*>(&l);
}

// Per-CU balance map: CU gets blocks id, id+256, id+512, id+768 (round-robin);
// slots {s,s+4,s+8,s+12} must sum to equal work. QMAP gives each CU 34 units.
__device__ __constant__ int QMAP[16] = {15,14,13,12, 8,9,10,11, 7,6,5,4, 0,1,2,3};

// ---------------- MFMA flash attention with exact-floor scores ----------------
// 1D grid 1024: bh = id&63 (fastest), qblk = QMAP[id>>6]. Block = 4 waves,
// 128 q-rows; wave owns 32 rows (two 16-row sub-tiles). K-tiles of 32.
// MFMA 16x16x32 layouts: A[m=lane&15][k=quad*8+j]; B[k=quad*8+j][n=lane&15];
// C/D row=quad*4+reg, col=lane&15.
__global__ __launch_bounds__(256, 4)
void attn_mfma(const float* __restrict__ Q, const float* __restrict__ K,
               const float* __restrict__ V, __hip_bfloat16* __restrict__ O)
{
    __shared__ __align__(16) short Khi[32][136];
    __shared__ __align__(16) short Klo[32][136];
    // Vt[hd][k]: 64B rows, group-swizzled: k-group g of row hd stored at
    // position g ^ ((hd>>2)&3). k-order inside groups preserved -> MFMA-legal.
    __shared__ __align__(16) short Vt[128][32];
    __shared__ __align__(16) short Ps[4][32][40];

    const int tid  = threadIdx.x;
    const int wave = tid >> 6;
    const int lane = tid & 63;
    const int quad = lane >> 4;
    const int n    = lane & 15;

    const int id   = blockIdx.x;
    const int bh   = id & 63;
    const int qblk = QMAP[id >> 6];
    const int b    = bh >> 4;
    const int h    = bh & 15;
    const int q0w  = qblk * 128 + wave * 32;

    const size_t inbase = ((size_t)b * TSEQ) * CEMB + (size_t)h * HD;

    const float  scale     = sqrtf(128.0f);
    const double dscale    = (double)scale;
    const float  inv_scale = 1.0f / scale;

    // ---- Q fragments (resident): hi/lo bf16 split ----
    bf16x8 qhi[2][4], qlo[2][4];
    #pragma unroll
    for (int s = 0; s < 2; ++s) {
        #pragma unroll
        for (int ks = 0; ks < 4; ++ks) {
            const float* qp = Q + inbase + (size_t)(q0w + 16 * s + n) * CEMB + 32 * ks + 8 * quad;
            float4 f0 = *(const float4*)qp;
            float4 f1 = *(const float4*)(qp + 4);
            float fv[8] = {f0.x, f0.y, f0.z, f0.w, f1.x, f1.y, f1.z, f1.w};
            bf16x8 h8, l8;
            #pragma unroll
            for (int j = 0; j < 8; ++j) {
                short hj, lj;
                split2(fv[j], hj, lj);
                h8[j] = hj; l8[j] = lj;
            }
            qhi[s][ks] = h8;
            qlo[s][ks] = l8;
        }
    }

    f32x4 oacc[2][8];
    #pragma unroll
    for (int s = 0; s < 2; ++s)
        #pragma unroll
        for (int nt = 0; nt < 8; ++nt)
            oacc[s][nt] = (f32x4){0.f, 0.f, 0.f, 0.f};

    float m_r[2][4], l_r[2][4];
    #pragma unroll
    for (int s = 0; s < 2; ++s)
        #pragma unroll
        for (int reg = 0; reg < 4; ++reg) { m_r[s][reg] = NEGF; l_r[s][reg] = 0.f; }

    const int nkt = 4 * (qblk + 1);

    for (int kt = 0; kt < nkt; ++kt) {
        const int k0 = kt * 32;
        __syncthreads();
        // ---- stage K (hi/lo split) and V (bf16, transposed + swizzled) ----
        #pragma unroll
        for (int it = 0; it < 4; ++it) {
            int idx = tid + 256 * it;      // 0..1023
            int r   = idx >> 5;            // 0..31 (r>>3 == it)
            int c4  = idx & 31;            // float4 within row
            size_t off = inbase + (size_t)(k0 + r) * CEMB + 4 * c4;
            float4 kv = *(const float4*)(K + off);
            float4 vv = *(const float4*)(V + off);
            short4 khi4, klo4;
            split2(kv.x, khi4.x, klo4.x); split2(kv.y, khi4.y, klo4.y);
            split2(kv.z, khi4.z, klo4.z); split2(kv.w, khi4.w, klo4.w);
            *(short4*)&Khi[r][4 * c4] = khi4;
            *(short4*)&Klo[r][4 * c4] = klo4;
            int pos = 8 * (it ^ (c4 & 3)) + (r & 7);
            Vt[4 * c4 + 0][pos] = f2bf(vv.x);
            Vt[4 * c4 + 1][pos] = f2bf(vv.y);
            Vt[4 * c4 + 2][pos] = f2bf(vv.z);
            Vt[4 * c4 + 3][pos] = f2bf(vv.w);
        }
        __syncthreads();

        if (k0 <= q0w + 31) {   // causal: wave has live rows in this K-tile
            // ---- S = Q·K^T via 3-term bf16-split MFMA ----
            f32x4 sacc[2][2];
            #pragma unroll
            for (int s = 0; s < 2; ++s)
                #pragma unroll
                for (int nt = 0; nt < 2; ++nt)
                    sacc[s][nt] = (f32x4){0.f, 0.f, 0.f, 0.f};

            #pragma unroll
            for (int ks = 0; ks < 4; ++ks) {
                #pragma unroll
                for (int nt = 0; nt < 2; ++nt) {
                    bf16x8 khf = *(const bf16x8*)&Khi[16 * nt + n][32 * ks + 8 * quad];
                    bf16x8 klf = *(const bf16x8*)&Klo[16 * nt + n][32 * ks + 8 * quad];
                    #pragma unroll
                    for (int s = 0; s < 2; ++s) {
                        sacc[s][nt] = __builtin_amdgcn_mfma_f32_16x16x32_bf16(qhi[s][ks], khf, sacc[s][nt], 0, 0, 0);
                        sacc[s][nt] = __builtin_amdgcn_mfma_f32_16x16x32_bf16(qhi[s][ks], klf, sacc[s][nt], 0, 0, 0);
                        sacc[s][nt] = __builtin_amdgcn_mfma_f32_16x16x32_bf16(qlo[s][ks], khf, sacc[s][nt], 0, 0, 0);
                    }
                }
            }

            // ---- floor + fp64 boundary fixup + online softmax, write P ----
            #pragma unroll
            for (int s = 0; s < 2; ++s) {
                float sc[2][4];
                #pragma unroll
                for (int nt = 0; nt < 2; ++nt) {
                    #pragma unroll
                    for (int reg = 0; reg < 4; ++reg) {
                        int qrow = q0w + 16 * s + 4 * quad + reg;
                        int kcol = k0 + 16 * nt + n;
                        if (kcol > qrow) { sc[nt][reg] = NEGF; continue; }
                        float sv = sacc[s][nt][reg] * inv_scale;
                        float f  = floorf(sv);
                        float fr = sv - f;
                        if (fr < WIN || fr > 1.0f - WIN) {
                            const float* qp = Q + inbase + (size_t)qrow * CEMB;
                            const float* kp = K + inbase + (size_t)kcol * CEMB;
                            double dd = 0.0;
                            for (int kk = 0; kk < HD; kk += 4)
                                dd += (double)qp[kk] * kp[kk] + (double)qp[kk + 1] * kp[kk + 1]
                                    + (double)qp[kk + 2] * kp[kk + 2] + (double)qp[kk + 3] * kp[kk + 3];
                            f = (float)floor(dd / dscale);
                        }
                        sc[nt][reg] = f;
                    }
                }
                float alphaL[4];
                #pragma unroll
                for (int reg = 0; reg < 4; ++reg) {
                    float tm = fmaxf(sc[0][reg], sc[1][reg]);
                    tm = fmaxf(tm, __shfl_xor(tm, 1));
                    tm = fmaxf(tm, __shfl_xor(tm, 2));
                    tm = fmaxf(tm, __shfl_xor(tm, 4));
                    tm = fmaxf(tm, __shfl_xor(tm, 8));
                    float mo = m_r[s][reg];
                    float mn = fmaxf(mo, tm);
                    float al = (mo < -1e29f) ? 0.0f : expf(mo - mn);
                    float p0 = (sc[0][reg] < -1e29f) ? 0.0f : expf(sc[0][reg] - mn);
                    float p1 = (sc[1][reg] < -1e29f) ? 0.0f : expf(sc[1][reg] - mn);
                    float ps = p0 + p1;
                    ps += __shfl_xor(ps, 1);
                    ps += __shfl_xor(ps, 2);
                    ps += __shfl_xor(ps, 4);
                    ps += __shfl_xor(ps, 8);
                    l_r[s][reg] = l_r[s][reg] * al + ps;
                    m_r[s][reg] = mn;
                    alphaL[reg] = al;
                    Ps[wave][16 * s + 4 * quad + reg][n]      = f2bf(p0);
                    Ps[wave][16 * s + 4 * quad + reg][16 + n] = f2bf(p1);
                }
                #pragma unroll
                for (int ntv = 0; ntv < 8; ++ntv) {
                    #pragma unroll
                    for (int reg = 0; reg < 4; ++reg)
                        oacc[s][ntv][reg] *= alphaL[reg];
                }
            }

            // ---- O += P·V: A-frag from Ps, B-frag b128 from swizzled Vt ----
            bf16x8 pfa[2];
            pfa[0] = *(const bf16x8*)&Ps[wave][n][8 * quad];
            pfa[1] = *(const bf16x8*)&Ps[wave][16 + n][8 * quad];
            #pragma unroll
            for (int ntv = 0; ntv < 8; ++ntv) {
                bf16x8 vf = *(const bf16x8*)&Vt[16 * ntv + n][8 * (quad ^ (n >> 2))];
                oacc[0][ntv] = __builtin_amdgcn_mfma_f32_16x16x32_bf16(pfa[0], vf, oacc[0][ntv], 0, 0, 0);
                oacc[1][ntv] = __builtin_amdgcn_mfma_f32_16x16x32_bf16(pfa[1], vf, oacc[1][ntv], 0, 0, 0);
            }
        }
    }

    // ---- normalize + write bf16 merged-head layout [b, t, h*128 + c] ----
    #pragma unroll
    for (int s = 0; s < 2; ++s) {
        #pragma unroll
        for (int reg = 0; reg < 4; ++reg) {
            float inv = 1.0f / l_r[s][reg];
            int qrow = q0w + 16 * s + 4 * quad + reg;
            __hip_bfloat16* op = O + ((size_t)b * TSEQ + qrow) * CEMB + (size_t)h * HD;
            #pragma unroll
            for (int ntv = 0; ntv < 8; ++ntv)
                op[16 * ntv + n] = __float2bfloat16(oacc[s][ntv][reg] * inv);
        }
    }
}

// ---------------- projection: out = X(bf16) @ W^T + bias, MFMA ----------------
// Tile 128x128, K-slab 32. Block 256 = 4 waves in 2x2; wave does 64x64 via
// 4x4 sub-tiles of 16x16x32 (one MFMA consumes the whole slab).
__global__ __launch_bounds__(256)
void proj_mfma(const __hip_bfloat16* __restrict__ X, const float* __restrict__ W,
               const float* __restrict__ bias, float* __restrict__ out)
{
    __shared__ __align__(16) short Xs[128][40];
    __shared__ __align__(16) short Ws[128][40];

    const int tid  = threadIdx.x;
    const int wave = tid >> 6;
    const int lane = tid & 63;
    const int quad = lane >> 4;
    const int n    = lane & 15;
    const int wm   = wave >> 1;
    const int wn   = wave & 1;

    const int m0 = blockIdx.y * 128;
    const int n0 = blockIdx.x * 128;

    f32x4 acc[4][4];
    #pragma unroll
    for (int i = 0; i < 4; ++i)
        #pragma unroll
        for (int j = 0; j < 4; ++j)
            acc[i][j] = (f32x4){0.f, 0.f, 0.f, 0.f};

    for (int k0 = 0; k0 < CEMB; k0 += 32) {
        __syncthreads();
        // X: bf16 direct, 128x32 = 512 16B-chunks
        #pragma unroll
        for (int ii = 0; ii < 2; ++ii) {
            int idx = tid + 256 * ii;          // 0..511
            int row = idx >> 2;                // 0..127
            int c   = idx & 3;                 // 16B group
            *(bf16x8*)&Xs[row][8 * c] =
                *(const bf16x8*)(X + (size_t)(m0 + row) * CEMB + k0 + 8 * c);
        }
        // W: fp32 -> bf16, 128x32 = 1024 float4
        #pragma unroll
        for (int ii = 0; ii < 4; ++ii) {
            int idx = tid + 256 * ii;          // 0..1023
            int row = idx >> 3;                // 0..127
            int c4  = idx & 7;
            float4 wv = *(const float4*)(W + (size_t)(n0 + row) * CEMB + k0 + 4 * c4);
            short4 w4;
            w4.x = f2bf(wv.x); w4.y = f2bf(wv.y); w4.z = f2bf(wv.z); w4.w = f2bf(wv.w);
            *(short4*)&Ws[row][4 * c4] = w4;
        }
        __syncthreads();

        bf16x8 a[4], bb[4];
        #pragma unroll
        for (int i = 0; i < 4; ++i)
            a[i] = *(const bf16x8*)&Xs[64 * wm + 16 * i + n][8 * quad];
        #pragma unroll
        for (int j = 0; j < 4; ++j)
            bb[j] = *(const bf16x8*)&Ws[64 * wn + 16 * j + n][8 * quad];
        #pragma unroll
        for (int i = 0; i < 4; ++i)
            #pragma unroll
            for (int j = 0; j < 4; ++j)
                acc[i][j] = __builtin_amdgcn_mfma_f32_16x16x32_bf16(a[i], bb[j], acc[i][j], 0, 0, 0);
    }

    #pragma unroll
    for (int j = 0; j < 4; ++j) {
        int col = n0 + 64 * wn + 16 * j + n;
        float bj = bias[col];
        #pragma unroll
        for (int i = 0; i < 4; ++i) {
            #pragma unroll
            for (int reg = 0; reg < 4; ++reg) {
                int row = m0 + 64 * wm + 16 * i + 4 * quad + reg;
                out[(size_t)row * CEMB + col] = acc[i][j][reg] + bj;
            }
        }
    }
}

extern "C" void kernel_launch(void* const* d_in, const int* in_sizes, int n_in,
                              void* d_out, int out_size, void* d_ws, size_t ws_size,
                              hipStream_t stream)
{
    // setup_inputs order: v, k, q, W_out, b_out
    const float* v    = (const float*)d_in[0];
    const float* k    = (const float*)d_in[1];
    const float* q    = (const float*)d_in[2];
    const float* W    = (const float*)d_in[3];
    const float* bias = (const float*)d_in[4];

    __hip_bfloat16* attn = (__hip_bfloat16*)d_ws;   // B*T*C bf16 = 32 MiB scratch
    float* out = (float*)d_out;

    attn_mfma<<<dim3(1024), 256, 0, stream>>>(q, k, v, attn);

    dim3 pgrid(CEMB / 128, (BATCH * TSEQ) / 128);   // (16, 64)
    proj_mfma<<<pgrid, 256, 0, stream>>>(attn, W, bias, out);
}